// Round 1
// 395.597 us; speedup vs baseline: 1.1409x; 1.1409x over previous
//
#include <hip/hip_runtime.h>

typedef unsigned short u16;
using bf16x8 = __attribute__((ext_vector_type(8))) __bf16;
using f32x4  = __attribute__((ext_vector_type(4))) float;
using u32x2  = __attribute__((ext_vector_type(2))) unsigned;
using u32x4  = __attribute__((ext_vector_type(4))) unsigned;

#define AS1 __attribute__((address_space(1)))
#define AS3 __attribute__((address_space(3)))

__device__ __forceinline__ void glds16(const u16* g, u16* l) {
  __builtin_amdgcn_global_load_lds((AS1 void*)const_cast<u16*>(g), (AS3 void*)l, 16, 0, 0);
}

__device__ __forceinline__ u16 f2bf(float f) {
  unsigned u = __float_as_uint(f);
  u += 0x7FFFu + ((u >> 16) & 1u);
  return (u16)(u >> 16);
}
__device__ __forceinline__ ushort4 cvt4(float4 v) {
  return make_ushort4(f2bf(v.x), f2bf(v.y), f2bf(v.z), f2bf(v.w));
}

__device__ __forceinline__ unsigned cvt_pk_bf16(float lo, float hi) {
  unsigned r;
  asm("v_cvt_pk_bf16_f32 %0, %1, %2" : "=v"(r) : "v"(lo), "v"(hi));
  return r;
}

// full quad exchange: X' = [Xq0, Yq0, Xq1, Yq1] rearranged so that after
// permlane32_swap + permlane16_swap:  X'' = [Xq0, Xq2, Yq0, Yq2] per-quarter
// sources (see derivation in session notes) — yields PV A-frag dword pairs.
__device__ __forceinline__ void quad_swap(unsigned& x, unsigned& y) {
  u32x2 a = __builtin_amdgcn_permlane32_swap(x, y, false, false);
  u32x2 b = __builtin_amdgcn_permlane16_swap(a[0], a[1], false, false);
  x = b[0];
  y = b[1];
}

// ---------------- one-shot fp32 -> bf16 conversion ----------------
__global__ __launch_bounds__(256) void cvt_kernel(const float4* __restrict__ hs,
    const float4* __restrict__ wq, const float4* __restrict__ wk,
    const float4* __restrict__ wv, const float4* __restrict__ wo, u16* __restrict__ dst) {
  const long stride = (long)gridDim.x * blockDim.x;
  for (long i = (long)blockIdx.x * blockDim.x + threadIdx.x; i < 3558400; i += stride) {
    const float4* src; long rel; u16* d;
    if (i < 1920000)      { src = hs; rel = i;           d = dst; }
    else if (i < 2329600) { src = wq; rel = i - 1920000; d = dst + 7680000; }
    else if (i < 2739200) { src = wk; rel = i - 2329600; d = dst + 9318400; }
    else if (i < 3148800) { src = wv; rel = i - 2739200; d = dst + 10956800; }
    else                  { src = wo; rel = i - 3148800; d = dst + 12595200; }
    *(ushort4*)(d + rel * 4) = cvt4(src[rel]);
  }
}

// ---------------- bf16 GEMM via global_load_lds (m97 structure) ----------------
template <int MODE, typename OT>
__device__ __forceinline__ void gemm_bf(const u16* __restrict__ A, const u16* __restrict__ W,
                                        const float* __restrict__ bias, OT* __restrict__ out,
                                        float scale, int M, u16* As, u16* Bs) {
  constexpr int K = 1280;
  const int m0 = blockIdx.x * 128, n0 = blockIdx.y * 128;
  const int tid = threadIdx.x, wid = tid >> 6, lane = tid & 63;
  const int lm = lane & 15, quad = lane >> 4;
  const int wm = (wid >> 1) * 64, wn = (wid & 1) * 64;

  f32x4 acc[4][4] = {};

  const int ch0 = wid * 64 + lane, ch1 = 256 + ch0;
  int rA0 = m0 + (ch0 >> 2); rA0 = rA0 < M ? rA0 : M - 1;
  int rA1 = m0 + (ch1 >> 2); rA1 = rA1 < M ? rA1 : M - 1;
  const int kc0 = (ch0 & 3) * 8, kc1 = (ch1 & 3) * 8;
  const u16* a0 = A + (size_t)rA0 * K + kc0;
  const u16* a1 = A + (size_t)rA1 * K + kc1;
  const u16* w0 = W + (size_t)(n0 + (ch0 >> 2)) * K + kc0;
  const u16* w1 = W + (size_t)(n0 + (ch1 >> 2)) * K + kc1;
  u16* lA0 = As + wid * 512; u16* lA1 = As + 2048 + wid * 512;
  u16* lB0 = Bs + wid * 512; u16* lB1 = Bs + 2048 + wid * 512;

  for (int kt = 0; kt < K; kt += 32) {
    __syncthreads();
    glds16(a0 + kt, lA0);
    glds16(a1 + kt, lA1);
    glds16(w0 + kt, lB0);
    glds16(w1 + kt, lB1);
    __syncthreads();
    bf16x8 af[4], bfr[4];
#pragma unroll
    for (int i = 0; i < 4; ++i) af[i] = *(const bf16x8*)(As + (wm + i * 16 + lm) * 32 + quad * 8);
#pragma unroll
    for (int j = 0; j < 4; ++j) bfr[j] = *(const bf16x8*)(Bs + (wn + j * 16 + lm) * 32 + quad * 8);
#pragma unroll
    for (int i = 0; i < 4; ++i)
#pragma unroll
      for (int j = 0; j < 4; ++j)
        acc[i][j] = __builtin_amdgcn_mfma_f32_16x16x32_bf16(af[i], bfr[j], acc[i][j], 0, 0, 0);
  }

#pragma unroll
  for (int j = 0; j < 4; ++j) {
    const int col = n0 + wn + j * 16 + lm;
    const float bb = bias ? bias[col] : 0.0f;
    const int hh = col >> 6, dd = col & 63;
#pragma unroll
    for (int i = 0; i < 4; ++i) {
      const int row0 = m0 + wm + i * 16 + quad * 4;
#pragma unroll
      for (int r = 0; r < 4; ++r) {
        const int row = row0 + r;
        if (row < M) {
          const float v = (acc[i][j][r] + bb) * scale;
          if (MODE == 0) {
            out[(size_t)row * 1280 + col] = (OT)v;
          } else {
            const int bidx = row / 1500, s = row - bidx * 1500;
            if (MODE == 1)
              out[((size_t)(bidx * 20 + hh) * 1500 + s) * 64 + dd] = (OT)f2bf(v);
            else
              out[((size_t)(bidx * 20 + hh) * 64 + dd) * 1504 + s] = (OT)f2bf(v);
          }
        }
      }
    }
  }
}

__global__ __launch_bounds__(256) void qkv_kernel(const u16* __restrict__ hs,
    const u16* __restrict__ Wq, const float* __restrict__ bq, const u16* __restrict__ Wk,
    const u16* __restrict__ Wv, const float* __restrict__ bv,
    u16* __restrict__ q_ws, u16* __restrict__ k_ws, u16* __restrict__ vt_ws, int M) {
  __shared__ __align__(16) u16 As[128 * 32];
  __shared__ __align__(16) u16 Bs[128 * 32];
  if (blockIdx.z == 0)
    gemm_bf<1, u16>(hs, Wq, bq, q_ws, 0.18033688f, M, As, Bs);  // 0.125*log2(e): exp2-domain
  else if (blockIdx.z == 1)
    gemm_bf<1, u16>(hs, Wk, nullptr, k_ws, 1.0f, M, As, Bs);
  else
    gemm_bf<2, u16>(hs, Wv, bv, vt_ws, 1.0f, M, As, Bs);
}

__global__ __launch_bounds__(256) void out_kernel(const u16* __restrict__ attn,
    const u16* __restrict__ Wo, const float* __restrict__ bo, float* __restrict__ out, int M) {
  __shared__ __align__(16) u16 As[128 * 32];
  __shared__ __align__(16) u16 Bs[128 * 32];
  gemm_bf<0, float>(attn, Wo, bo, out, 1.0f, M, As, Bs);
}

// ---------------- Flash attention: swapped QK^T, in-register softmax/P ----------------
// Q,K: [b,h,1500,64] bf16 (Q pre-scaled by 0.125*log2e); Vt: [b,h,64,1504] bf16.
// 4 waves; wave owns 32 q-rows as 2 groups of 16. S^T = mfma(K,Q): each lane owns one
// q-row (lm) with kpos = t*16+quad*4+r -> per-lane scalar m/l, 2-shfl reductions.
// P -> bf16 A-frags fully in-register: cvt_pk pairs + permlane32/16_swap quad exchange.
// K/V staged via global_load_lds (pre-swizzled source, linear LDS dest), dbuf, 1 barrier/iter.
__global__ __launch_bounds__(256, 4) void attn_kernel(const u16* __restrict__ Qm,
    const u16* __restrict__ Km, const u16* __restrict__ Vtm, u16* __restrict__ Out) {
  const int qt = blockIdx.x, h = blockIdx.y, b = blockIdx.z;
  const int bh = b * 20 + h;
  const int tid = threadIdx.x, wid = tid >> 6, lane = tid & 63;
  const int lm = lane & 15, quad = lane >> 4;

  __shared__ __align__(16) u16 Ks[2][64 * 64];    // [kpos][d], XOR-chunk swizzled
  __shared__ __align__(16) u16 Vts[2][64 * 64];   // [d][kpos], swizzled

  const u16* Qb = Qm + (size_t)bh * (1500 * 64);
  const u16* Kb = Km + (size_t)bh * (1500 * 64);
  const u16* Vb = Vtm + (size_t)bh * (64 * 1504);

  bf16x8 qf[2][2];
#pragma unroll
  for (int g = 0; g < 2; ++g) {
    int qrow = qt * 128 + wid * 32 + g * 16 + lm;
    if (qrow > 1499) qrow = 1499;                 // dup rows masked at store
    qf[g][0] = *(const bf16x8*)(Qb + (size_t)qrow * 64 + quad * 8);
    qf[g][1] = *(const bf16x8*)(Qb + (size_t)qrow * 64 + 32 + quad * 8);
  }

  // staging geometry: thread (rr, cc) stages 16B chunks; swizzle on the GLOBAL side,
  // LDS dest is linear (wave-uniform base + lane*16B) as global_load_lds requires.
  const int rr = tid >> 3, cc = tid & 7;
  const int s0 = (cc ^ (rr & 7)) * 8;             // (rr+32)&7 == rr&7

  auto stage = [&](int kt, int bi) {
    int kr0 = kt + rr;      if (kr0 > 1499) kr0 = 1499;
    int kr1 = kt + rr + 32; if (kr1 > 1499) kr1 = 1499;
    int vcol = kt + s0;     if (vcol > 1496) vcol = 1496;   // keep V reads in-bounds/finite
    u16* lk = &Ks[bi][0] + wid * 512;
    u16* lv = &Vts[bi][0] + wid * 512;
    glds16(Kb + (size_t)kr0 * 64 + s0, lk);
    glds16(Kb + (size_t)kr1 * 64 + s0, lk + 2048);
    glds16(Vb + (size_t)rr * 1504 + vcol, lv);
    glds16(Vb + (size_t)(rr + 32) * 1504 + vcol, lv + 2048);
  };

  stage(0, 0);
  __syncthreads();

  float m_s[2] = {-1e30f, -1e30f};
  float l_s[2] = {0.f, 0.f};
  f32x4 o_acc[2][4] = {};

  for (int it = 0; it < 24; ++it) {
    const int cur = it & 1;
    if (it + 1 < 24) stage((it + 1) * 64, cur ^ 1);   // async into other buffer

    // S^T = K Q^T : st[g][t] lane holds q-row lm, kpos = t*16 + quad*4 + r
    f32x4 st[2][4] = {};
#pragma unroll
    for (int kk = 0; kk < 2; ++kk) {
#pragma unroll
      for (int t = 0; t < 4; ++t) {
        const bf16x8 kf = *(const bf16x8*)(&Ks[cur][(t * 16 + lm) * 64 + (((kk * 4 + quad) ^ (lm & 7)) * 8)]);
        st[0][t] = __builtin_amdgcn_mfma_f32_16x16x32_bf16(kf, qf[0][kk], st[0][t], 0, 0, 0);
        st[1][t] = __builtin_amdgcn_mfma_f32_16x16x32_bf16(kf, qf[1][kk], st[1][t], 0, 0, 0);
      }
    }
    if (it == 23) {                               // ragged tile: kpos = 1472 + t*16+quad*4+r
#pragma unroll
      for (int t = 0; t < 4; ++t)
#pragma unroll
        for (int r = 0; r < 4; ++r)
          if (t * 16 + quad * 4 + r >= 28) { st[0][t][r] = -1e30f; st[1][t][r] = -1e30f; }
    }

    float alpha_s[2];
    bf16x8 pf[2][2];
#pragma unroll
    for (int g = 0; g < 2; ++g) {
      // row max: in-lane tree over 16 vals + 2 cross-quad shuffles
      float a0 = fmaxf(fmaxf(st[g][0][0], st[g][0][1]), fmaxf(st[g][0][2], st[g][0][3]));
      float a1 = fmaxf(fmaxf(st[g][1][0], st[g][1][1]), fmaxf(st[g][1][2], st[g][1][3]));
      float a2 = fmaxf(fmaxf(st[g][2][0], st[g][2][1]), fmaxf(st[g][2][2], st[g][2][3]));
      float a3 = fmaxf(fmaxf(st[g][3][0], st[g][3][1]), fmaxf(st[g][3][2], st[g][3][3]));
      float rm = fmaxf(fmaxf(a0, a1), fmaxf(a2, a3));
      rm = fmaxf(rm, __shfl_xor(rm, 16));
      rm = fmaxf(rm, __shfl_xor(rm, 32));
      const float mn = fmaxf(m_s[g], rm);
      const float al = exp2f(m_s[g] - mn);
      m_s[g] = mn;
      alpha_s[g] = al;

      float rs = 0.f;
      unsigned A[4], B[4];
#pragma unroll
      for (int t = 0; t < 4; ++t) {
        const float p0 = exp2f(st[g][t][0] - mn);
        const float p1 = exp2f(st[g][t][1] - mn);
        const float p2 = exp2f(st[g][t][2] - mn);
        const float p3 = exp2f(st[g][t][3] - mn);
        rs += (p0 + p1) + (p2 + p3);
        A[t] = cvt_pk_bf16(p0, p1);
        B[t] = cvt_pk_bf16(p2, p3);
      }
      rs += __shfl_xor(rs, 16);
      rs += __shfl_xor(rs, 32);
      l_s[g] = l_s[g] * al + rs;

      // redistribute P into PV A-frag layout: lane ends with P[lm][kk*32+quad*8 .. +7]
#pragma unroll
      for (int kk = 0; kk < 2; ++kk) {
        unsigned x0 = A[2 * kk], x1 = A[2 * kk + 1];
        quad_swap(x0, x1);                        // -> dwords 0 (k+0,1) and 2 (k+4,5)
        unsigned y0 = B[2 * kk], y1 = B[2 * kk + 1];
        quad_swap(y0, y1);                        // -> dwords 1 (k+2,3) and 3 (k+6,7)
        u32x4 w; w[0] = x0; w[1] = y0; w[2] = x1; w[3] = y1;
        pf[g][kk] = __builtin_bit_cast(bf16x8, w);
      }
    }

    // rescale O in accumulator layout (q-row = quad*4+r): pull alpha from lane lm=q-row
#pragma unroll
    for (int g = 0; g < 2; ++g)
#pragma unroll
      for (int r = 0; r < 4; ++r) {
        const float ao = __shfl(alpha_s[g], quad * 4 + r);
#pragma unroll
        for (int t = 0; t < 4; ++t) o_acc[g][t][r] *= ao;
      }

    // O += P V
#pragma unroll
    for (int kk = 0; kk < 2; ++kk) {
#pragma unroll
      for (int t = 0; t < 4; ++t) {
        const bf16x8 vf = *(const bf16x8*)(&Vts[cur][(t * 16 + lm) * 64 + (((kk * 4 + quad) ^ (lm & 7)) * 8)]);
        o_acc[0][t] = __builtin_amdgcn_mfma_f32_16x16x32_bf16(pf[0][kk], vf, o_acc[0][t], 0, 0, 0);
        o_acc[1][t] = __builtin_amdgcn_mfma_f32_16x16x32_bf16(pf[1][kk], vf, o_acc[1][t], 0, 0, 0);
      }
    }

    __syncthreads();                              // drains glds (vmcnt) + orders dbuf swap
  }

#pragma unroll
  for (int g = 0; g < 2; ++g)
#pragma unroll
    for (int r = 0; r < 4; ++r) {
      const float lr = __shfl(l_s[g], quad * 4 + r);
      const float inv = 1.0f / lr;
      const int qg = qt * 128 + wid * 32 + g * 16 + quad * 4 + r;
      if (qg < 1500) {
#pragma unroll
        for (int t = 0; t < 4; ++t)
          Out[((size_t)(b * 1500 + qg)) * 1280 + h * 64 + t * 16 + lm] =
              f2bf(o_acc[g][t][r] * inv);
      }
    }
}

extern "C" void kernel_launch(void* const* d_in, const int* in_sizes, int n_in,
                              void* d_out, int out_size, void* d_ws, size_t ws_size,
                              hipStream_t stream) {
  const float* hs = (const float*)d_in[0];
  const float* Wq = (const float*)d_in[2];
  const float* bq = (const float*)d_in[3];
  const float* Wk = (const float*)d_in[4];
  const float* Wv = (const float*)d_in[5];
  const float* bv = (const float*)d_in[6];
  const float* Wo = (const float*)d_in[7];
  const float* bo = (const float*)d_in[8];

  u16* cvt     = (u16*)d_ws;
  u16* hs_bf   = cvt;                          // [6000,1280]
  u16* Wq_bf   = cvt + 7680000;
  u16* Wk_bf   = cvt + 9318400;
  u16* Wv_bf   = cvt + 10956800;
  u16* Wo_bf   = cvt + 12595200;
  u16* q_ws    = cvt + 14233600;               // [4,20,1500,64]
  u16* k_ws    = q_ws + 7680000;
  u16* vt_ws   = k_ws + 7680000;               // [4,20,64,1504] (+64 pad)
  u16* attn_ws = vt_ws + 7700480 + 64;         // [6000,1280]
  const int M = 6000;

  dim3 blk(256);
  hipLaunchKernelGGL(cvt_kernel, dim3(2048), blk, 0, stream,
                     (const float4*)hs, (const float4*)Wq, (const float4*)Wk,
                     (const float4*)Wv, (const float4*)Wo, cvt);
  hipLaunchKernelGGL(qkv_kernel, dim3(47, 10, 3), blk, 0, stream,
                     hs_bf, Wq_bf, bq, Wk_bf, Wv_bf, bv, q_ws, k_ws, vt_ws, M);
  hipLaunchKernelGGL(attn_kernel, dim3(12, 20, 4), blk, 0, stream,
                     q_ws, k_ws, vt_ws, attn_ws);
  hipLaunchKernelGGL(out_kernel, dim3(47, 10, 1), blk, 0, stream,
                     attn_ws, Wo_bf, bo, (float*)d_out, M);
}

// Round 2
// 371.928 us; speedup vs baseline: 1.2136x; 1.0636x over previous
//
#include <hip/hip_runtime.h>

typedef unsigned short u16;
using bf16x8 = __attribute__((ext_vector_type(8))) __bf16;
using f32x4  = __attribute__((ext_vector_type(4))) float;
using u32x2  = __attribute__((ext_vector_type(2))) unsigned;
using u32x4  = __attribute__((ext_vector_type(4))) unsigned;

#define AS1 __attribute__((address_space(1)))
#define AS3 __attribute__((address_space(3)))

__device__ __forceinline__ void glds16(const u16* g, u16* l) {
  __builtin_amdgcn_global_load_lds((AS1 void*)const_cast<u16*>(g), (AS3 void*)l, 16, 0, 0);
}

__device__ __forceinline__ u16 f2bf(float f) {
  unsigned u = __float_as_uint(f);
  u += 0x7FFFu + ((u >> 16) & 1u);
  return (u16)(u >> 16);
}
__device__ __forceinline__ ushort4 cvt4(float4 v) {
  return make_ushort4(f2bf(v.x), f2bf(v.y), f2bf(v.z), f2bf(v.w));
}

__device__ __forceinline__ unsigned cvt_pk_bf16(float lo, float hi) {
  unsigned r;
  asm("v_cvt_pk_bf16_f32 %0, %1, %2" : "=v"(r) : "v"(lo), "v"(hi));
  return r;
}

// full quad exchange via permlane32_swap + permlane16_swap (see r0 derivation):
// yields PV A-frag dword pairs from per-lane packed P values.
__device__ __forceinline__ void quad_swap(unsigned& x, unsigned& y) {
  u32x2 a = __builtin_amdgcn_permlane32_swap(x, y, false, false);
  u32x2 b = __builtin_amdgcn_permlane16_swap(a[0], a[1], false, false);
  x = b[0];
  y = b[1];
}

// ---------------- one-shot fp32 -> bf16 conversion ----------------
__global__ __launch_bounds__(256) void cvt_kernel(const float4* __restrict__ hs,
    const float4* __restrict__ wq, const float4* __restrict__ wk,
    const float4* __restrict__ wv, const float4* __restrict__ wo, u16* __restrict__ dst) {
  const long stride = (long)gridDim.x * blockDim.x;
  for (long i = (long)blockIdx.x * blockDim.x + threadIdx.x; i < 3558400; i += stride) {
    const float4* src; long rel; u16* d;
    if (i < 1920000)      { src = hs; rel = i;           d = dst; }
    else if (i < 2329600) { src = wq; rel = i - 1920000; d = dst + 7680000; }
    else if (i < 2739200) { src = wk; rel = i - 2329600; d = dst + 9318400; }
    else if (i < 3148800) { src = wv; rel = i - 2739200; d = dst + 10956800; }
    else                  { src = wo; rel = i - 3148800; d = dst + 12595200; }
    *(ushort4*)(d + rel * 4) = cvt4(src[rel]);
  }
}

// ---------------- bf16 GEMM via global_load_lds (m97 structure) ----------------
// m0/n0 passed in: callers do XCD-banded tile remapping for L2 locality.
template <int MODE, typename OT>
__device__ __forceinline__ void gemm_bf(const u16* __restrict__ A, const u16* __restrict__ W,
                                        const float* __restrict__ bias, OT* __restrict__ out,
                                        float scale, int M, u16* As, u16* Bs,
                                        int m0, int n0) {
  constexpr int K = 1280;
  const int tid = threadIdx.x, wid = tid >> 6, lane = tid & 63;
  const int lm = lane & 15, quad = lane >> 4;
  const int wm = (wid >> 1) * 64, wn = (wid & 1) * 64;

  f32x4 acc[4][4] = {};

  const int ch0 = wid * 64 + lane, ch1 = 256 + ch0;
  int rA0 = m0 + (ch0 >> 2); rA0 = rA0 < M ? rA0 : M - 1;
  int rA1 = m0 + (ch1 >> 2); rA1 = rA1 < M ? rA1 : M - 1;
  const int kc0 = (ch0 & 3) * 8, kc1 = (ch1 & 3) * 8;
  const u16* a0 = A + (size_t)rA0 * K + kc0;
  const u16* a1 = A + (size_t)rA1 * K + kc1;
  const u16* w0 = W + (size_t)(n0 + (ch0 >> 2)) * K + kc0;
  const u16* w1 = W + (size_t)(n0 + (ch1 >> 2)) * K + kc1;
  u16* lA0 = As + wid * 512; u16* lA1 = As + 2048 + wid * 512;
  u16* lB0 = Bs + wid * 512; u16* lB1 = Bs + 2048 + wid * 512;

  for (int kt = 0; kt < K; kt += 32) {
    __syncthreads();
    glds16(a0 + kt, lA0);
    glds16(a1 + kt, lA1);
    glds16(w0 + kt, lB0);
    glds16(w1 + kt, lB1);
    __syncthreads();
    bf16x8 af[4], bfr[4];
#pragma unroll
    for (int i = 0; i < 4; ++i) af[i] = *(const bf16x8*)(As + (wm + i * 16 + lm) * 32 + quad * 8);
#pragma unroll
    for (int j = 0; j < 4; ++j) bfr[j] = *(const bf16x8*)(Bs + (wn + j * 16 + lm) * 32 + quad * 8);
#pragma unroll
    for (int i = 0; i < 4; ++i)
#pragma unroll
      for (int j = 0; j < 4; ++j)
        acc[i][j] = __builtin_amdgcn_mfma_f32_16x16x32_bf16(af[i], bfr[j], acc[i][j], 0, 0, 0);
  }

#pragma unroll
  for (int j = 0; j < 4; ++j) {
    const int col = n0 + wn + j * 16 + lm;
    const float bb = bias ? bias[col] : 0.0f;
    const int hh = col >> 6, dd = col & 63;
#pragma unroll
    for (int i = 0; i < 4; ++i) {
      const int row0 = m0 + wm + i * 16 + quad * 4;
#pragma unroll
      for (int r = 0; r < 4; ++r) {
        const int row = row0 + r;
        if (row < M) {
          const float v = (acc[i][j][r] + bb) * scale;
          if (MODE == 0) {
            out[(size_t)row * 1280 + col] = (OT)v;
          } else {
            const int bidx = row / 1500, s = row - bidx * 1500;
            if (MODE == 1)
              out[((size_t)(bidx * 20 + hh) * 1500 + s) * 64 + dd] = (OT)f2bf(v);
            else
              out[((size_t)(bidx * 20 + hh) * 64 + dd) * 1504 + s] = (OT)f2bf(v);
          }
        }
      }
    }
  }
}

// XCD-banded remap (bijective, m204-style): each XCD owns a contiguous band of
// A-row panels (6,6,6,6,6,6,6,5 over 47) -> per-XCD A working set 1.9MB (L2-fit).
// x innermost so each B panel is consumed while L2-hot.
__global__ __launch_bounds__(256) void qkv_kernel(const u16* __restrict__ hs,
    const u16* __restrict__ Wq, const float* __restrict__ bq, const u16* __restrict__ Wk,
    const u16* __restrict__ Wv, const float* __restrict__ bv,
    u16* __restrict__ q_ws, u16* __restrict__ k_ws, u16* __restrict__ vt_ws, int M) {
  __shared__ __align__(16) u16 As[128 * 32];
  __shared__ __align__(16) u16 Bs[128 * 32];
  const int n = blockIdx.x;                     // grid = 1440 (8 XCD * 180)
  const int xcd = n & 7, j = n >> 3;            // j in [0,180)
  const int x = xcd * 6 + (j % 6);
  if (x >= 47) return;                          // block-uniform: safe before barriers
  const int yz = j / 6;                         // [0,30)
  const int y = yz % 10, z = yz / 10;
  const int m0 = x * 128, n0 = y * 128;
  if (z == 0)
    gemm_bf<1, u16>(hs, Wq, bq, q_ws, 0.18033688f, M, As, Bs, m0, n0);  // 0.125*log2(e)
  else if (z == 1)
    gemm_bf<1, u16>(hs, Wk, nullptr, k_ws, 1.0f, M, As, Bs, m0, n0);
  else
    gemm_bf<2, u16>(hs, Wv, bv, vt_ws, 1.0f, M, As, Bs, m0, n0);
}

__global__ __launch_bounds__(256) void out_kernel(const u16* __restrict__ attn,
    const u16* __restrict__ Wo, const float* __restrict__ bo, float* __restrict__ out, int M) {
  __shared__ __align__(16) u16 As[128 * 32];
  __shared__ __align__(16) u16 Bs[128 * 32];
  const int n = blockIdx.x;                     // grid = 480 (8 XCD * 60)
  const int xcd = n & 7, j = n >> 3;            // j in [0,60)
  const int x = xcd * 6 + (j % 6);
  if (x >= 47) return;
  const int y = j / 6;                          // [0,10)
  gemm_bf<0, float>(attn, Wo, bo, out, 1.0f, M, As, Bs, x * 128, y * 128);
}

// ---------------- Flash attention: swapped QK^T, in-register softmax/P ----------------
// Q,K: [b,h,1500,64] bf16 (Q pre-scaled by 0.125*log2e); Vt: [b,h,64,1504] bf16.
// 4 waves; wave owns 32 q-rows as 2 groups of 16. S^T = mfma(K,Q): each lane owns one
// q-row (lm) with kpos = t*16+quad*4+r -> per-lane scalar m/l, 2-shfl reductions.
// P -> bf16 A-frags fully in-register: cvt_pk pairs + permlane32/16_swap quad exchange.
// K/V staged via global_load_lds (pre-swizzled source, linear LDS dest), dbuf, 1 barrier/iter.
__global__ __launch_bounds__(256, 4) void attn_kernel(const u16* __restrict__ Qm,
    const u16* __restrict__ Km, const u16* __restrict__ Vtm, u16* __restrict__ Out) {
  const int qt = blockIdx.x, h = blockIdx.y, b = blockIdx.z;
  const int bh = b * 20 + h;
  const int tid = threadIdx.x, wid = tid >> 6, lane = tid & 63;
  const int lm = lane & 15, quad = lane >> 4;

  __shared__ __align__(16) u16 Ks[2][64 * 64];    // [kpos][d], XOR-chunk swizzled
  __shared__ __align__(16) u16 Vts[2][64 * 64];   // [d][kpos], swizzled

  const u16* Qb = Qm + (size_t)bh * (1500 * 64);
  const u16* Kb = Km + (size_t)bh * (1500 * 64);
  const u16* Vb = Vtm + (size_t)bh * (64 * 1504);

  bf16x8 qf[2][2];
#pragma unroll
  for (int g = 0; g < 2; ++g) {
    int qrow = qt * 128 + wid * 32 + g * 16 + lm;
    if (qrow > 1499) qrow = 1499;                 // dup rows masked at store
    qf[g][0] = *(const bf16x8*)(Qb + (size_t)qrow * 64 + quad * 8);
    qf[g][1] = *(const bf16x8*)(Qb + (size_t)qrow * 64 + 32 + quad * 8);
  }

  // staging geometry: thread (rr, cc) stages 16B chunks; swizzle on the GLOBAL side,
  // LDS dest is linear (wave-uniform base + lane*16B) as global_load_lds requires.
  const int rr = tid >> 3, cc = tid & 7;
  const int s0 = (cc ^ (rr & 7)) * 8;             // (rr+32)&7 == rr&7

  auto stage = [&](int kt, int bi) {
    int kr0 = kt + rr;      if (kr0 > 1499) kr0 = 1499;
    int kr1 = kt + rr + 32; if (kr1 > 1499) kr1 = 1499;
    int vcol = kt + s0;     if (vcol > 1496) vcol = 1496;   // keep V reads in-bounds/finite
    u16* lk = &Ks[bi][0] + wid * 512;
    u16* lv = &Vts[bi][0] + wid * 512;
    glds16(Kb + (size_t)kr0 * 64 + s0, lk);
    glds16(Kb + (size_t)kr1 * 64 + s0, lk + 2048);
    glds16(Vb + (size_t)rr * 1504 + vcol, lv);
    glds16(Vb + (size_t)(rr + 32) * 1504 + vcol, lv + 2048);
  };

  stage(0, 0);
  __syncthreads();

  float m_s[2] = {-1e30f, -1e30f};
  float l_s[2] = {0.f, 0.f};
  f32x4 o_acc[2][4] = {};

  for (int it = 0; it < 24; ++it) {
    const int cur = it & 1;
    if (it + 1 < 24) stage((it + 1) * 64, cur ^ 1);   // async into other buffer

    // S^T = K Q^T : st[g][t] lane holds q-row lm, kpos = t*16 + quad*4 + r
    f32x4 st[2][4] = {};
    __builtin_amdgcn_s_setprio(1);
#pragma unroll
    for (int kk = 0; kk < 2; ++kk) {
#pragma unroll
      for (int t = 0; t < 4; ++t) {
        const bf16x8 kf = *(const bf16x8*)(&Ks[cur][(t * 16 + lm) * 64 + (((kk * 4 + quad) ^ (lm & 7)) * 8)]);
        st[0][t] = __builtin_amdgcn_mfma_f32_16x16x32_bf16(kf, qf[0][kk], st[0][t], 0, 0, 0);
        st[1][t] = __builtin_amdgcn_mfma_f32_16x16x32_bf16(kf, qf[1][kk], st[1][t], 0, 0, 0);
      }
    }
    __builtin_amdgcn_s_setprio(0);
    if (it == 23) {                               // ragged tile: kpos = 1472 + t*16+quad*4+r
#pragma unroll
      for (int t = 0; t < 4; ++t)
#pragma unroll
        for (int r = 0; r < 4; ++r)
          if (t * 16 + quad * 4 + r >= 28) { st[0][t][r] = -1e30f; st[1][t][r] = -1e30f; }
    }

    float alpha_s[2];
    bf16x8 pf[2][2];
#pragma unroll
    for (int g = 0; g < 2; ++g) {
      // row max: in-lane tree over 16 vals + 2 cross-quad shuffles
      float a0 = fmaxf(fmaxf(st[g][0][0], st[g][0][1]), fmaxf(st[g][0][2], st[g][0][3]));
      float a1 = fmaxf(fmaxf(st[g][1][0], st[g][1][1]), fmaxf(st[g][1][2], st[g][1][3]));
      float a2 = fmaxf(fmaxf(st[g][2][0], st[g][2][1]), fmaxf(st[g][2][2], st[g][2][3]));
      float a3 = fmaxf(fmaxf(st[g][3][0], st[g][3][1]), fmaxf(st[g][3][2], st[g][3][3]));
      float rm = fmaxf(fmaxf(a0, a1), fmaxf(a2, a3));
      rm = fmaxf(rm, __shfl_xor(rm, 16));
      rm = fmaxf(rm, __shfl_xor(rm, 32));
      const float mn = fmaxf(m_s[g], rm);
      const float al = exp2f(m_s[g] - mn);
      m_s[g] = mn;
      alpha_s[g] = al;

      float rs = 0.f;
      unsigned A[4], B[4];
#pragma unroll
      for (int t = 0; t < 4; ++t) {
        const float p0 = exp2f(st[g][t][0] - mn);
        const float p1 = exp2f(st[g][t][1] - mn);
        const float p2 = exp2f(st[g][t][2] - mn);
        const float p3 = exp2f(st[g][t][3] - mn);
        rs += (p0 + p1) + (p2 + p3);
        A[t] = cvt_pk_bf16(p0, p1);
        B[t] = cvt_pk_bf16(p2, p3);
      }
      rs += __shfl_xor(rs, 16);
      rs += __shfl_xor(rs, 32);
      l_s[g] = l_s[g] * al + rs;

      // redistribute P into PV A-frag layout: lane ends with P[lm][kk*32+quad*8 .. +7]
#pragma unroll
      for (int kk = 0; kk < 2; ++kk) {
        unsigned x0 = A[2 * kk], x1 = A[2 * kk + 1];
        quad_swap(x0, x1);                        // -> dwords 0 (k+0,1) and 2 (k+4,5)
        unsigned y0 = B[2 * kk], y1 = B[2 * kk + 1];
        quad_swap(y0, y1);                        // -> dwords 1 (k+2,3) and 3 (k+6,7)
        u32x4 w; w[0] = x0; w[1] = y0; w[2] = x1; w[3] = y1;
        pf[g][kk] = __builtin_bit_cast(bf16x8, w);
      }
    }

    // rescale O in accumulator layout (q-row = quad*4+r): pull alpha from lane lm=q-row
#pragma unroll
    for (int g = 0; g < 2; ++g)
#pragma unroll
      for (int r = 0; r < 4; ++r) {
        const float ao = __shfl(alpha_s[g], quad * 4 + r);
#pragma unroll
        for (int t = 0; t < 4; ++t) o_acc[g][t][r] *= ao;
      }

    // O += P V
    __builtin_amdgcn_s_setprio(1);
#pragma unroll
    for (int kk = 0; kk < 2; ++kk) {
#pragma unroll
      for (int t = 0; t < 4; ++t) {
        const bf16x8 vf = *(const bf16x8*)(&Vts[cur][(t * 16 + lm) * 64 + (((kk * 4 + quad) ^ (lm & 7)) * 8)]);
        o_acc[0][t] = __builtin_amdgcn_mfma_f32_16x16x32_bf16(pf[0][kk], vf, o_acc[0][t], 0, 0, 0);
        o_acc[1][t] = __builtin_amdgcn_mfma_f32_16x16x32_bf16(pf[1][kk], vf, o_acc[1][t], 0, 0, 0);
      }
    }
    __builtin_amdgcn_s_setprio(0);

    __syncthreads();                              // drains glds (vmcnt) + orders dbuf swap
  }

#pragma unroll
  for (int g = 0; g < 2; ++g)
#pragma unroll
    for (int r = 0; r < 4; ++r) {
      const float lr = __shfl(l_s[g], quad * 4 + r);
      const float inv = 1.0f / lr;
      const int qg = qt * 128 + wid * 32 + g * 16 + quad * 4 + r;
      if (qg < 1500) {
#pragma unroll
        for (int t = 0; t < 4; ++t)
          Out[((size_t)(b * 1500 + qg)) * 1280 + h * 64 + t * 16 + lm] =
              f2bf(o_acc[g][t][r] * inv);
      }
    }
}

extern "C" void kernel_launch(void* const* d_in, const int* in_sizes, int n_in,
                              void* d_out, int out_size, void* d_ws, size_t ws_size,
                              hipStream_t stream) {
  const float* hs = (const float*)d_in[0];
  const float* Wq = (const float*)d_in[2];
  const float* bq = (const float*)d_in[3];
  const float* Wk = (const float*)d_in[4];
  const float* Wv = (const float*)d_in[5];
  const float* bv = (const float*)d_in[6];
  const float* Wo = (const float*)d_in[7];
  const float* bo = (const float*)d_in[8];

  u16* cvt     = (u16*)d_ws;
  u16* hs_bf   = cvt;                          // [6000,1280]
  u16* Wq_bf   = cvt + 7680000;
  u16* Wk_bf   = cvt + 9318400;
  u16* Wv_bf   = cvt + 10956800;
  u16* Wo_bf   = cvt + 12595200;
  u16* q_ws    = cvt + 14233600;               // [4,20,1500,64]
  u16* k_ws    = q_ws + 7680000;
  u16* vt_ws   = k_ws + 7680000;               // [4,20,64,1504] (+64 pad)
  u16* attn_ws = vt_ws + 7700480 + 64;         // [6000,1280]
  const int M = 6000;

  dim3 blk(256);
  hipLaunchKernelGGL(cvt_kernel, dim3(2048), blk, 0, stream,
                     (const float4*)hs, (const float4*)Wq, (const float4*)Wk,
                     (const float4*)Wv, (const float4*)Wo, cvt);
  hipLaunchKernelGGL(qkv_kernel, dim3(1440), blk, 0, stream,
                     hs_bf, Wq_bf, bq, Wk_bf, Wv_bf, bv, q_ws, k_ws, vt_ws, M);
  hipLaunchKernelGGL(attn_kernel, dim3(12, 20, 4), blk, 0, stream,
                     q_ws, k_ws, vt_ws, attn_ws);
  hipLaunchKernelGGL(out_kernel, dim3(480), blk, 0, stream,
                     attn_ws, Wo_bf, bo, (float*)d_out, M);
}